// Round 10
// baseline (137.797 us; speedup 1.0000x reference)
//
#include <hip/hip_runtime.h>

// NSLayer: per 8x8 matrix x: A = I - x x^T (symmetric),
// out = (1+w7) x + sum_{k=1..7} w_{k-1} A^k x.
//
// R16 = R14 (coalesced I/O + LDS transpose + packed power compute, measured
// <40.5us: fell below the harness fillBuffer dispatches in the profile) +
// multi-tile pipelining:
//  - Each block processes NT=4 tiles (128 matrices each) in a loop.
//  - Next tile's 8x global_load_dwordx4 are issued into REGISTERS right
//    after the current tile's LDS stage-write; they fly during the ~2600cyc
//    compute phase, so the vmcnt wait at the next stage-write is ~free
//    (T14 async-STAGE: issue-early / write-late). Removes the one exposed
//    HBM round-trip per wave that the single-shot R14 paid.
//  - LDS unchanged: 32KB/block, wave-private 8KB, swizzle
//    s(C) = C ^ (((C>>4)&3)<<1) (involutive, conflict-free all 4 phases).
//    lgkmcnt(0) at loop top orders drain-reads vs re-stage-writes.
//  - Compute unchanged (proven R12/R14): Gram + pswap merge, packed
//    v_pk_fma_f32 power iteration with op_sel broadcast.
// Register budget: R14 ~76 VGPR + 32 prefetch = ~110 < 128 (demotion cliff
// at ~210, R11 lesson). Health: WRITE must stay ~65.5MB, VGPR <= ~125.
//
// History: R8/R10/R12/R13 scattered-I/O variants all 46-52us (~2 TB/s
// request-rate wall); R14 coalesced -> <40.5us; floors: mem ~20us,
// compute ~17us. R9 lesson: never force high waves_per_eu (spill).

typedef float v2f __attribute__((ext_vector_type(2)));

#define NT 4   // tiles (of 128 matrices) per block

// ---- packed fp32 primitives (encodings proven R11/R12/R14) ----
__device__ __forceinline__ v2f pk_mul(v2f a, v2f b) {
    v2f d;
    asm("v_pk_mul_f32 %0, %1, %2" : "=v"(d) : "v"(a), "v"(b));
    return d;
}
__device__ __forceinline__ void pk_fma(v2f &acc, v2f a, v2f b) {
    asm("v_pk_fma_f32 %0, %1, %2, %0" : "+v"(acc) : "v"(a), "v"(b));
}
__device__ __forceinline__ v2f pk_mul_lo(v2f a, v2f b) {
    v2f d;
    asm("v_pk_mul_f32 %0, %1, %2 op_sel:[0,0] op_sel_hi:[0,1]"
        : "=v"(d) : "v"(a), "v"(b));
    return d;
}
__device__ __forceinline__ void pk_fma_lo(v2f &acc, v2f a, v2f b) {
    asm("v_pk_fma_f32 %0, %1, %2, %0 op_sel:[0,0,0] op_sel_hi:[0,1,1]"
        : "+v"(acc) : "v"(a), "v"(b));
}
__device__ __forceinline__ void pk_fma_hi(v2f &acc, v2f a, v2f b) {
    asm("v_pk_fma_f32 %0, %1, %2, %0 op_sel:[1,0,0] op_sel_hi:[1,1,1]"
        : "+v"(acc) : "v"(a), "v"(b));
}

// lane^1 partner swap as DPP quad_perm [1,0,3,2] (ctrl 0xB1), proven R10.
__device__ __forceinline__ float pswap(float x)
{
    return __builtin_bit_cast(float,
        __builtin_amdgcn_update_dpp(0, __builtin_bit_cast(int, x),
                                    0xB1, 0xF, 0xF, true));
}

#define AE(p, q) A[(p) < (q) ? (p) : (q)][(p) < (q) ? (q) : (p)]

// One power step: n = A*y (slab matvec, packed), y <- n, acc += wk * n.
#define POW_STEP(wk)                                                      \
    {                                                                     \
        const v2f wv = (v2f){(wk), (wk)};                                 \
        _Pragma("unroll")                                                 \
        for (int j = 0; j < 2; ++j) {                                     \
            v2f n[8];                                                     \
            _Pragma("unroll")                                             \
            for (int p = 0; p < 8; ++p) {                                 \
                v2f a = pk_mul_lo(Ar[p][0], y[j][0]);                     \
                pk_fma_hi(a, Ar[p][0], y[j][1]);                          \
                pk_fma_lo(a, Ar[p][1], y[j][2]);                          \
                pk_fma_hi(a, Ar[p][1], y[j][3]);                          \
                pk_fma_lo(a, Ar[p][2], y[j][4]);                          \
                pk_fma_hi(a, Ar[p][2], y[j][5]);                          \
                pk_fma_lo(a, Ar[p][3], y[j][6]);                          \
                pk_fma_hi(a, Ar[p][3], y[j][7]);                          \
                n[p] = a;                                                 \
            }                                                             \
            _Pragma("unroll")                                             \
            for (int p = 0; p < 8; ++p) {                                 \
                y[j][p] = n[p];                                           \
                pk_fma(acc[j][p], wv, n[p]);                              \
            }                                                             \
        }                                                                 \
    }

__global__ __launch_bounds__(256)
void ns_poly_kernel(const float* __restrict__ in,
                    const float* __restrict__ wp,
                    float* __restrict__ out)
{
    __shared__ float4 lds[2048];                      // 32 KB: 4 waves x 8 KB

    const int tid  = threadIdx.x;
    const int wave = tid >> 6;
    const int lane = tid & 63;
    const int l    = lane >> 1;                       // matrix-in-wave 0..31
    const int h    = lane & 1;                        // column-half owner

    const float w0 = wp[0], w1 = wp[1], w2 = wp[2], w3 = wp[3];
    const float w4 = wp[4], w5 = wp[5], w6 = wp[6], w7 = wp[7];

    float4* L = lds + wave * 512;                     // wave-private 8 KB

    // this wave's first chunk (float4 units) for tile t:
    //   base(t) = (blockIdx.x*NT + t)*128*16 + wave*32*16
    const size_t base0 =
        ((size_t)blockIdx.x * NT * 128 + (size_t)wave * 32) * 16;
    const float4* __restrict__ gin  = reinterpret_cast<const float4*>(in);
    float4*       __restrict__ gout = reinterpret_cast<float4*>(out);

    // ---- prologue: prefetch tile 0 into registers (contiguous) ----
    float4 r[8];
#pragma unroll
    for (int it = 0; it < 8; ++it)
        r[it] = gin[base0 + it * 64 + lane];

    for (int t = 0; t < NT; ++t) {
        const size_t base = base0 + (size_t)t * 128 * 16;

        // order: previous drain's LDS reads must finish before overwrite
        asm volatile("s_waitcnt lgkmcnt(0)" ::: "memory");

        // ---- stage: prefetched regs -> swizzled LDS ----
#pragma unroll
        for (int it = 0; it < 8; ++it) {
            const int C = it * 64 + lane;
            L[C ^ (((C >> 4) & 3) << 1)] = r[it];
        }

        // ---- issue next tile's loads (fly during compute) ----
        if (t + 1 < NT) {
            const size_t nbase = base + 128 * 16;
#pragma unroll
            for (int it = 0; it < 8; ++it)
                r[it] = gin[nbase + it * 64 + lane];
        }

        asm volatile("s_waitcnt lgkmcnt(0)" ::: "memory");

        // ---- fragment read: rows g=0..7, my col-half (natural layout) ----
        v2f y[2][8];
#pragma unroll
        for (int g = 0; g < 8; ++g) {
            const int f4 = (l * 16 + g * 2 + h) ^ ((l & 3) << 1);
            const float4 v = L[f4];
            y[0][g] = (v2f){v.x, v.y};
            y[1][g] = (v2f){v.z, v.w};
        }

        // ---- partial Gram over my 4 columns (upper triangle) ----
        float S[8][8];
#pragma unroll
        for (int p = 0; p < 8; ++p)
#pragma unroll
            for (int q = p; q < 8; ++q) {
                v2f a = pk_mul(y[0][p], y[0][q]);
                pk_fma(a, y[1][p], y[1][q]);
                S[p][q] = a.x + a.y;
            }

        // ---- A = I - S - partner(S): pswap at same (p,q) ----
        float A[8][8];
#pragma unroll
        for (int p = 0; p < 8; ++p)
#pragma unroll
            for (int q = p; q < 8; ++q) {
                const float other = pswap(S[p][q]);
                A[p][q] = (p == q ? 1.0f : 0.0f) - S[p][q] - other;
            }

        // ---- pack A rows into q-pairs for op_sel broadcast ----
        v2f Ar[8][4];
#pragma unroll
        for (int p = 0; p < 8; ++p)
#pragma unroll
            for (int jq = 0; jq < 4; ++jq)
                Ar[p][jq] = (v2f){AE(p, 2 * jq), AE(p, 2 * jq + 1)};

        // ---- power iteration: acc = (1+w7) x; 7x { y<-Ay; acc+=wk y } ----
        v2f acc[2][8];
        const v2f w7v = (v2f){1.0f + w7, 1.0f + w7};
#pragma unroll
        for (int j = 0; j < 2; ++j)
#pragma unroll
            for (int p = 0; p < 8; ++p)
                acc[j][p] = pk_mul(w7v, y[j][p]);

        POW_STEP(w0);
        POW_STEP(w1);
        POW_STEP(w2);
        POW_STEP(w3);
        POW_STEP(w4);
        POW_STEP(w5);
        POW_STEP(w6);

        // ---- fragment write back to LDS (swizzled) ----
#pragma unroll
        for (int g = 0; g < 8; ++g) {
            const int f4 = (l * 16 + g * 2 + h) ^ ((l & 3) << 1);
            L[f4] = make_float4(acc[0][g].x, acc[0][g].y,
                                acc[1][g].x, acc[1][g].y);
        }
        asm volatile("s_waitcnt lgkmcnt(0)" ::: "memory");

        // ---- drain: swizzled LDS -> contiguous global stores ----
#pragma unroll
        for (int it = 0; it < 8; ++it) {
            const int C = it * 64 + lane;
            gout[base + C] = L[C ^ (((C >> 4) & 3) << 1)];
        }
    }
}

extern "C" void kernel_launch(void* const* d_in, const int* in_sizes, int n_in,
                              void* d_out, int out_size, void* d_ws, size_t ws_size,
                              hipStream_t stream)
{
    const float* in = (const float*)d_in[0];
    const float* w  = (const float*)d_in[1];
    float* outp     = (float*)d_out;

    const int nmat   = in_sizes[0] / 64;        // 262144 matrices
    const int blocks = nmat / (128 * NT);       // 512 blocks of 4 tiles
    ns_poly_kernel<<<blocks, 256, 0, stream>>>(in, w, outp);
}

// Round 11
// 136.928 us; speedup vs baseline: 1.0063x; 1.0063x over previous
//
#include <hip/hip_runtime.h>

// NSLayer: per 8x8 matrix x: A = I - x x^T (symmetric),
// out = (1+w7) x + sum_{k=1..7} w_{k-1} A^k x.
//
// R17 = R16 structure + __launch_bounds__(256, 2) restored.
// R16 post-mortem: bare __launch_bounds__(256) let the allocator chase
// 5 waves/SIMD -> clamped to 96 VGPR and SPILLED the r[8] prefetch block:
// WRITE 65.5->128MB, FETCH 33->51MB (scratch traffic), 59us. Same failure
// class as R9/R11. (256,2) min-occupancy declaration gives a 256-VGPR
// budget -> prefetch stays in registers (R8=116, R12=76 VGPR precedent).
//
// Structure (R14/R16, all proven):
//  - Coalesced I/O: every global instruction is lane i <-> bytes
//    [16i,16i+16) of a contiguous 1KB block (fixes the 2 TB/s scattered-
//    request wall of R8-R13; R14 measured <40.5us).
//  - LDS transpose staging, wave-private 8KB, chunk swizzle
//    s(C) = C ^ (((C>>4)&3)<<1) (involutive, bank-floor all 4 phases;
//    measured 1 conflict-cycle/instr = accounting floor, benign).
//  - NT=4 tiles per block; next tile's 8x global_load_dwordx4 issued into
//    registers right after the current stage-write, flying during the
//    ~2600cyc compute (T14 issue-early/write-late) -> hides the HBM
//    round-trip the single-shot R14 paid per wave.
//  - Compute (proven R12): Gram + pswap(DPP quad_perm) merge, packed
//    v_pk_fma_f32 power iteration with op_sel broadcast.
// Health: WRITE ~65.5MB & FETCH ~33MB (spill gone), VGPR ~110, no LDS
// conflict growth. If clean but still ~39us -> prefetch adds nothing,
// latency-structure floor reached.

typedef float v2f __attribute__((ext_vector_type(2)));

#define NT 4   // tiles (of 128 matrices) per block

// ---- packed fp32 primitives (encodings proven R11/R12/R14) ----
__device__ __forceinline__ v2f pk_mul(v2f a, v2f b) {
    v2f d;
    asm("v_pk_mul_f32 %0, %1, %2" : "=v"(d) : "v"(a), "v"(b));
    return d;
}
__device__ __forceinline__ void pk_fma(v2f &acc, v2f a, v2f b) {
    asm("v_pk_fma_f32 %0, %1, %2, %0" : "+v"(acc) : "v"(a), "v"(b));
}
__device__ __forceinline__ v2f pk_mul_lo(v2f a, v2f b) {
    v2f d;
    asm("v_pk_mul_f32 %0, %1, %2 op_sel:[0,0] op_sel_hi:[0,1]"
        : "=v"(d) : "v"(a), "v"(b));
    return d;
}
__device__ __forceinline__ void pk_fma_lo(v2f &acc, v2f a, v2f b) {
    asm("v_pk_fma_f32 %0, %1, %2, %0 op_sel:[0,0,0] op_sel_hi:[0,1,1]"
        : "+v"(acc) : "v"(a), "v"(b));
}
__device__ __forceinline__ void pk_fma_hi(v2f &acc, v2f a, v2f b) {
    asm("v_pk_fma_f32 %0, %1, %2, %0 op_sel:[1,0,0] op_sel_hi:[1,1,1]"
        : "+v"(acc) : "v"(a), "v"(b));
}

// lane^1 partner swap as DPP quad_perm [1,0,3,2] (ctrl 0xB1), proven R10.
__device__ __forceinline__ float pswap(float x)
{
    return __builtin_bit_cast(float,
        __builtin_amdgcn_update_dpp(0, __builtin_bit_cast(int, x),
                                    0xB1, 0xF, 0xF, true));
}

#define AE(p, q) A[(p) < (q) ? (p) : (q)][(p) < (q) ? (q) : (p)]

// One power step: n = A*y (slab matvec, packed), y <- n, acc += wk * n.
#define POW_STEP(wk)                                                      \
    {                                                                     \
        const v2f wv = (v2f){(wk), (wk)};                                 \
        _Pragma("unroll")                                                 \
        for (int j = 0; j < 2; ++j) {                                     \
            v2f n[8];                                                     \
            _Pragma("unroll")                                             \
            for (int p = 0; p < 8; ++p) {                                 \
                v2f a = pk_mul_lo(Ar[p][0], y[j][0]);                     \
                pk_fma_hi(a, Ar[p][0], y[j][1]);                          \
                pk_fma_lo(a, Ar[p][1], y[j][2]);                          \
                pk_fma_hi(a, Ar[p][1], y[j][3]);                          \
                pk_fma_lo(a, Ar[p][2], y[j][4]);                          \
                pk_fma_hi(a, Ar[p][2], y[j][5]);                          \
                pk_fma_lo(a, Ar[p][3], y[j][6]);                          \
                pk_fma_hi(a, Ar[p][3], y[j][7]);                          \
                n[p] = a;                                                 \
            }                                                             \
            _Pragma("unroll")                                             \
            for (int p = 0; p < 8; ++p) {                                 \
                y[j][p] = n[p];                                           \
                pk_fma(acc[j][p], wv, n[p]);                              \
            }                                                             \
        }                                                                 \
    }

__global__ __launch_bounds__(256, 2)
void ns_poly_kernel(const float* __restrict__ in,
                    const float* __restrict__ wp,
                    float* __restrict__ out)
{
    __shared__ float4 lds[2048];                      // 32 KB: 4 waves x 8 KB

    const int tid  = threadIdx.x;
    const int wave = tid >> 6;
    const int lane = tid & 63;
    const int l    = lane >> 1;                       // matrix-in-wave 0..31
    const int h    = lane & 1;                        // column-half owner

    const float w0 = wp[0], w1 = wp[1], w2 = wp[2], w3 = wp[3];
    const float w4 = wp[4], w5 = wp[5], w6 = wp[6], w7 = wp[7];

    float4* L = lds + wave * 512;                     // wave-private 8 KB

    // this wave's first chunk (float4 units) for tile t:
    //   base(t) = (blockIdx.x*NT + t)*128*16 + wave*32*16
    const size_t base0 =
        ((size_t)blockIdx.x * NT * 128 + (size_t)wave * 32) * 16;
    const float4* __restrict__ gin  = reinterpret_cast<const float4*>(in);
    float4*       __restrict__ gout = reinterpret_cast<float4*>(out);

    // ---- prologue: prefetch tile 0 into registers (contiguous) ----
    float4 r[8];
#pragma unroll
    for (int it = 0; it < 8; ++it)
        r[it] = gin[base0 + it * 64 + lane];

    for (int t = 0; t < NT; ++t) {
        const size_t base = base0 + (size_t)t * 128 * 16;

        // order: previous drain's LDS reads must finish before overwrite
        asm volatile("s_waitcnt lgkmcnt(0)" ::: "memory");

        // ---- stage: prefetched regs -> swizzled LDS ----
#pragma unroll
        for (int it = 0; it < 8; ++it) {
            const int C = it * 64 + lane;
            L[C ^ (((C >> 4) & 3) << 1)] = r[it];
        }

        // ---- issue next tile's loads (fly during compute) ----
        if (t + 1 < NT) {
            const size_t nbase = base + 128 * 16;
#pragma unroll
            for (int it = 0; it < 8; ++it)
                r[it] = gin[nbase + it * 64 + lane];
        }

        asm volatile("s_waitcnt lgkmcnt(0)" ::: "memory");

        // ---- fragment read: rows g=0..7, my col-half (natural layout) ----
        v2f y[2][8];
#pragma unroll
        for (int g = 0; g < 8; ++g) {
            const int f4 = (l * 16 + g * 2 + h) ^ ((l & 3) << 1);
            const float4 v = L[f4];
            y[0][g] = (v2f){v.x, v.y};
            y[1][g] = (v2f){v.z, v.w};
        }

        // ---- partial Gram over my 4 columns (upper triangle) ----
        float S[8][8];
#pragma unroll
        for (int p = 0; p < 8; ++p)
#pragma unroll
            for (int q = p; q < 8; ++q) {
                v2f a = pk_mul(y[0][p], y[0][q]);
                pk_fma(a, y[1][p], y[1][q]);
                S[p][q] = a.x + a.y;
            }

        // ---- A = I - S - partner(S): pswap at same (p,q) ----
        float A[8][8];
#pragma unroll
        for (int p = 0; p < 8; ++p)
#pragma unroll
            for (int q = p; q < 8; ++q) {
                const float other = pswap(S[p][q]);
                A[p][q] = (p == q ? 1.0f : 0.0f) - S[p][q] - other;
            }

        // ---- pack A rows into q-pairs for op_sel broadcast ----
        v2f Ar[8][4];
#pragma unroll
        for (int p = 0; p < 8; ++p)
#pragma unroll
            for (int jq = 0; jq < 4; ++jq)
                Ar[p][jq] = (v2f){AE(p, 2 * jq), AE(p, 2 * jq + 1)};

        // ---- power iteration: acc = (1+w7) x; 7x { y<-Ay; acc+=wk y } ----
        v2f acc[2][8];
        const v2f w7v = (v2f){1.0f + w7, 1.0f + w7};
#pragma unroll
        for (int j = 0; j < 2; ++j)
#pragma unroll
            for (int p = 0; p < 8; ++p)
                acc[j][p] = pk_mul(w7v, y[j][p]);

        POW_STEP(w0);
        POW_STEP(w1);
        POW_STEP(w2);
        POW_STEP(w3);
        POW_STEP(w4);
        POW_STEP(w5);
        POW_STEP(w6);

        // ---- fragment write back to LDS (swizzled) ----
#pragma unroll
        for (int g = 0; g < 8; ++g) {
            const int f4 = (l * 16 + g * 2 + h) ^ ((l & 3) << 1);
            L[f4] = make_float4(acc[0][g].x, acc[0][g].y,
                                acc[1][g].x, acc[1][g].y);
        }
        asm volatile("s_waitcnt lgkmcnt(0)" ::: "memory");

        // ---- drain: swizzled LDS -> contiguous global stores ----
#pragma unroll
        for (int it = 0; it < 8; ++it) {
            const int C = it * 64 + lane;
            gout[base + C] = L[C ^ (((C >> 4) & 3) << 1)];
        }
    }
}

extern "C" void kernel_launch(void* const* d_in, const int* in_sizes, int n_in,
                              void* d_out, int out_size, void* d_ws, size_t ws_size,
                              hipStream_t stream)
{
    const float* in = (const float*)d_in[0];
    const float* w  = (const float*)d_in[1];
    float* outp     = (float*)d_out;

    const int nmat   = in_sizes[0] / 64;        // 262144 matrices
    const int blocks = nmat / (128 * NT);       // 512 blocks of 4 tiles
    ns_poly_kernel<<<blocks, 256, 0, stream>>>(in, w, outp);
}

// Round 12
// 121.452 us; speedup vs baseline: 1.1346x; 1.1274x over previous
//
#include <hip/hip_runtime.h>

// NSLayer: per 8x8 matrix x: A = I - x x^T (symmetric),
// out = (1+w7) x + sum_{k=1..7} w_{k-1} A^k x.
//
// R18: async staging via __builtin_amdgcn_global_load_lds (width=16) +
// per-wave double-buffered LDS. R16/R17 post-mortem: register-held
// prefetch (r[8] = 32 VGPR) was spilled by the allocator's occupancy
// heuristic (96 VGPR target) REGARDLESS of __launch_bounds__(256,2) —
// the 2nd arg is a min-occupancy guarantee, not a register budget. Fix:
// DMA global->LDS directly; staging uses ZERO registers, completion is
// vmcnt-counted, loads stay in flight across the whole compute phase.
//
// DMA writes linearly (wave-uniform base + lane*16), so LDS dest is
// LINEAR and the SWIZZLE moves to the per-lane GLOBAL source address
// (m173 pattern): L[C] = G[s(C)], s(C) = C ^ (((C>>4)&3)<<1) involutive
// => same data placement as R14; frag-read/write & drain formulas
// unchanged (proven). s permutes 16B chunks within 256B groups -> each
// wave load still covers one contiguous 1KB block (coalescing kept).
//
// Per-tile pipeline (NT=4 tiles/block, buffers cur/nxt, NO barriers --
// all LDS traffic is wave-private):
//   lgkmcnt(0)                   ; prior drain's ds_reads done
//   issue 8x gll -> nxt (t+1)    ; async DMA
//   s_waitcnt vmcnt(8)           ; tile t landed; 8 new stay in flight
//   frag-read cur -> Gram -> A -> packed power iteration -> frag-write cur
//   lgkmcnt(0)                   ; frag-writes visible
//   drain: cur -> contiguous global stores
//   swap(cur, nxt)
// vmcnt ledger (stores count in vmcnt on CDNA): steady state 24
// outstanding, oldest 16 = gll(t)+stores(t-1) -> vmcnt(8) exact; first
// iter 16 outstanding -> waits gll(0); last iter (no issue) 16 -> waits
// gll(NT-1). Uniform vmcnt(8) everywhere.
//
// Compute (proven R12/R14): Gram + pswap (DPP quad_perm 0xB1) merge,
// packed v_pk_fma_f32 power iteration with op_sel broadcast.
// Health: WRITE ~65.5MB / FETCH ~33MB (spill gone), VGPR ~90-100,
// LDS 65536. History: scattered I/O = 2TB/s wall (R8-R13); R14
// coalesced+LDS <40.5us; R16/R17 reg-prefetch spilled (59us).

typedef float v2f __attribute__((ext_vector_type(2)));

#define NT 4   // tiles (of 128 matrices) per block

// ---- packed fp32 primitives (encodings proven R11/R12/R14) ----
__device__ __forceinline__ v2f pk_mul(v2f a, v2f b) {
    v2f d;
    asm("v_pk_mul_f32 %0, %1, %2" : "=v"(d) : "v"(a), "v"(b));
    return d;
}
__device__ __forceinline__ void pk_fma(v2f &acc, v2f a, v2f b) {
    asm("v_pk_fma_f32 %0, %1, %2, %0" : "+v"(acc) : "v"(a), "v"(b));
}
__device__ __forceinline__ v2f pk_mul_lo(v2f a, v2f b) {
    v2f d;
    asm("v_pk_mul_f32 %0, %1, %2 op_sel:[0,0] op_sel_hi:[0,1]"
        : "=v"(d) : "v"(a), "v"(b));
    return d;
}
__device__ __forceinline__ void pk_fma_lo(v2f &acc, v2f a, v2f b) {
    asm("v_pk_fma_f32 %0, %1, %2, %0 op_sel:[0,0,0] op_sel_hi:[0,1,1]"
        : "+v"(acc) : "v"(a), "v"(b));
}
__device__ __forceinline__ void pk_fma_hi(v2f &acc, v2f a, v2f b) {
    asm("v_pk_fma_f32 %0, %1, %2, %0 op_sel:[1,0,0] op_sel_hi:[1,1,1]"
        : "+v"(acc) : "v"(a), "v"(b));
}

// lane^1 partner swap as DPP quad_perm [1,0,3,2] (ctrl 0xB1), proven R10.
__device__ __forceinline__ float pswap(float x)
{
    return __builtin_bit_cast(float,
        __builtin_amdgcn_update_dpp(0, __builtin_bit_cast(int, x),
                                    0xB1, 0xF, 0xF, true));
}

// async DMA: 16B per lane, LDS dest = uniform base + lane*16 (linear).
#define GLOAD_LDS16(gp, lp)                                               \
    __builtin_amdgcn_global_load_lds(                                     \
        (const __attribute__((address_space(1))) void*)(gp),              \
        (__attribute__((address_space(3))) void*)(lp), 16, 0, 0)

#define AE(p, q) A[(p) < (q) ? (p) : (q)][(p) < (q) ? (q) : (p)]

// One power step: n = A*y (slab matvec, packed), y <- n, acc += wk * n.
#define POW_STEP(wk)                                                      \
    {                                                                     \
        const v2f wv = (v2f){(wk), (wk)};                                 \
        _Pragma("unroll")                                                 \
        for (int j = 0; j < 2; ++j) {                                     \
            v2f n[8];                                                     \
            _Pragma("unroll")                                             \
            for (int p = 0; p < 8; ++p) {                                 \
                v2f a = pk_mul_lo(Ar[p][0], y[j][0]);                     \
                pk_fma_hi(a, Ar[p][0], y[j][1]);                          \
                pk_fma_lo(a, Ar[p][1], y[j][2]);                          \
                pk_fma_hi(a, Ar[p][1], y[j][3]);                          \
                pk_fma_lo(a, Ar[p][2], y[j][4]);                          \
                pk_fma_hi(a, Ar[p][2], y[j][5]);                          \
                pk_fma_lo(a, Ar[p][3], y[j][6]);                          \
                pk_fma_hi(a, Ar[p][3], y[j][7]);                          \
                n[p] = a;                                                 \
            }                                                             \
            _Pragma("unroll")                                             \
            for (int p = 0; p < 8; ++p) {                                 \
                y[j][p] = n[p];                                           \
                pk_fma(acc[j][p], wv, n[p]);                              \
            }                                                             \
        }                                                                 \
    }

__global__ __launch_bounds__(256, 2)
void ns_poly_kernel(const float* __restrict__ in,
                    const float* __restrict__ wp,
                    float* __restrict__ out)
{
    __shared__ float4 lds[4096];                      // 64 KB: 4 waves x 2 x 8 KB

    const int tid  = threadIdx.x;
    const int wave = tid >> 6;
    const int lane = tid & 63;
    const int l    = lane >> 1;                       // matrix-in-wave 0..31
    const int h    = lane & 1;                        // column-half owner

    const float w0 = wp[0], w1 = wp[1], w2 = wp[2], w3 = wp[3];
    const float w4 = wp[4], w5 = wp[5], w6 = wp[6], w7 = wp[7];

    float4* cur = lds + wave * 1024;                  // wave-private buffers
    float4* nxt = cur + 512;

    // this wave's first chunk (float4 units) for tile t:
    //   base(t) = (blockIdx.x*NT + t)*128*16 + wave*32*16
    const size_t base0 =
        ((size_t)blockIdx.x * NT * 128 + (size_t)wave * 32) * 16;
    const float4* __restrict__ gin  = reinterpret_cast<const float4*>(in);
    float4*       __restrict__ gout = reinterpret_cast<float4*>(out);

    // pre-swizzled per-lane source chunk offsets: src(it) = s(it*64+lane)
    int srcs[8];
#pragma unroll
    for (int it = 0; it < 8; ++it) {
        const int C = it * 64 + lane;
        srcs[it] = C ^ (((C >> 4) & 3) << 1);
    }

    // ---- prologue: DMA tile 0 into cur ----
#pragma unroll
    for (int it = 0; it < 8; ++it)
        GLOAD_LDS16(gin + base0 + srcs[it], cur + it * 64);

    for (int t = 0; t < NT; ++t) {
        const size_t base = base0 + (size_t)t * 128 * 16;

        // prior drain's ds_reads of nxt must be done before DMA overwrites
        asm volatile("s_waitcnt lgkmcnt(0)" ::: "memory");

        // ---- issue next tile's DMA (flies through the compute phase) ----
        if (t + 1 < NT) {
            const size_t nbase = base + 128 * 16;
#pragma unroll
            for (int it = 0; it < 8; ++it)
                GLOAD_LDS16(gin + nbase + srcs[it], nxt + it * 64);
        }

        // tile t's DMA landed; the 8 new loads stay in flight (never 0)
        asm volatile("s_waitcnt vmcnt(8)" ::: "memory");
        __builtin_amdgcn_sched_barrier(0);

        // ---- fragment read: rows g=0..7, my col-half (natural layout) ----
        v2f y[2][8];
#pragma unroll
        for (int g = 0; g < 8; ++g) {
            const int f4 = (l * 16 + g * 2 + h) ^ ((l & 3) << 1);
            const float4 v = cur[f4];
            y[0][g] = (v2f){v.x, v.y};
            y[1][g] = (v2f){v.z, v.w};
        }

        // ---- partial Gram over my 4 columns (upper triangle) ----
        float S[8][8];
#pragma unroll
        for (int p = 0; p < 8; ++p)
#pragma unroll
            for (int q = p; q < 8; ++q) {
                v2f a = pk_mul(y[0][p], y[0][q]);
                pk_fma(a, y[1][p], y[1][q]);
                S[p][q] = a.x + a.y;
            }

        // ---- A = I - S - partner(S): pswap at same (p,q) ----
        float A[8][8];
#pragma unroll
        for (int p = 0; p < 8; ++p)
#pragma unroll
            for (int q = p; q < 8; ++q) {
                const float other = pswap(S[p][q]);
                A[p][q] = (p == q ? 1.0f : 0.0f) - S[p][q] - other;
            }

        // ---- pack A rows into q-pairs for op_sel broadcast ----
        v2f Ar[8][4];
#pragma unroll
        for (int p = 0; p < 8; ++p)
#pragma unroll
            for (int jq = 0; jq < 4; ++jq)
                Ar[p][jq] = (v2f){AE(p, 2 * jq), AE(p, 2 * jq + 1)};

        // ---- power iteration: acc = (1+w7) x; 7x { y<-Ay; acc+=wk y } ----
        v2f acc[2][8];
        const v2f w7v = (v2f){1.0f + w7, 1.0f + w7};
#pragma unroll
        for (int j = 0; j < 2; ++j)
#pragma unroll
            for (int p = 0; p < 8; ++p)
                acc[j][p] = pk_mul(w7v, y[j][p]);

        POW_STEP(w0);
        POW_STEP(w1);
        POW_STEP(w2);
        POW_STEP(w3);
        POW_STEP(w4);
        POW_STEP(w5);
        POW_STEP(w6);

        // ---- fragment write back to LDS (swizzled positions) ----
#pragma unroll
        for (int g = 0; g < 8; ++g) {
            const int f4 = (l * 16 + g * 2 + h) ^ ((l & 3) << 1);
            cur[f4] = make_float4(acc[0][g].x, acc[0][g].y,
                                  acc[1][g].x, acc[1][g].y);
        }
        asm volatile("s_waitcnt lgkmcnt(0)" ::: "memory");

        // ---- drain: LDS -> contiguous global stores ----
#pragma unroll
        for (int it = 0; it < 8; ++it) {
            const int C = it * 64 + lane;
            gout[base + C] = cur[C ^ (((C >> 4) & 3) << 1)];
        }

        float4* tmp = cur; cur = nxt; nxt = tmp;
    }
}

extern "C" void kernel_launch(void* const* d_in, const int* in_sizes, int n_in,
                              void* d_out, int out_size, void* d_ws, size_t ws_size,
                              hipStream_t stream)
{
    const float* in = (const float*)d_in[0];
    const float* w  = (const float*)d_in[1];
    float* outp     = (float*)d_out;

    const int nmat   = in_sizes[0] / 64;        // 262144 matrices
    const int blocks = nmat / (128 * NT);       // 512 blocks of 4 tiles
    ns_poly_kernel<<<blocks, 256, 0, stream>>>(in, w, outp);
}

// Round 13
// 119.590 us; speedup vs baseline: 1.1522x; 1.0156x over previous
//
#include <hip/hip_runtime.h>

// NSLayer: per 8x8 matrix x: A = I - x x^T (symmetric),
// out = (1+w7) x + sum_{k=1..7} w_{k-1} A^k x.
//
// R19: occupancy > pipeline depth. R18 (DMA + per-wave double buffer,
// 64KB/block) measured 41.5us, clean traffic (FETCH 33 / WRITE 65.5MB,
// VGPR 108) but Occupancy 13-14% (LDS-capped: 2 blocks/CU = 2 waves/SIMD)
// and VALUBusy 40% -> each wave idle ~60% in dependent-phase latency the
// prefetch could not hide. VALU-busy time ~16.6us and memory floor ~16us
// are both ~2.5x below the wall => raise TLP:
//  - SINGLE 8KB buffer per wave (32KB/block): LDS allows 5 blocks/CU,
//    VGPR 108 caps 4 waves/SIMD -> 16 waves/CU = 50% ceiling (2x R18).
//  - NT=1, grid 2048 blocks (8 queued/CU) -> natural stagger, no tail.
//  - Exposed DMA wait (~900cyc) per tile is now hidden by 4-way wave
//    interleave (guide m219/m238: TLP at high occupancy subsumes staging
//    splits — the reverse of R18's trade).
// Unchanged (proven R12/R14/R18): global_load_lds width=16 to LINEAR LDS
// with PRE-SWIZZLED global source s(C)=C^(((C>>4)&3)<<1) (involutive);
// frag read/write formulas; Gram + pswap (DPP 0xB1) merge; packed
// v_pk_fma_f32 power iteration with op_sel broadcast.
// Health: LDS 32768, VGPR ~105-110, FETCH ~33MB, WRITE ~65.5MB.
// History: scattered I/O = 2TB/s wall (R8-R13); reg-prefetch spills at
// allocator's whim (R16/R17); launch_bounds 2nd arg is a min, not a
// budget (R17).

typedef float v2f __attribute__((ext_vector_type(2)));

// ---- packed fp32 primitives (encodings proven R11/R12/R14) ----
__device__ __forceinline__ v2f pk_mul(v2f a, v2f b) {
    v2f d;
    asm("v_pk_mul_f32 %0, %1, %2" : "=v"(d) : "v"(a), "v"(b));
    return d;
}
__device__ __forceinline__ void pk_fma(v2f &acc, v2f a, v2f b) {
    asm("v_pk_fma_f32 %0, %1, %2, %0" : "+v"(acc) : "v"(a), "v"(b));
}
__device__ __forceinline__ v2f pk_mul_lo(v2f a, v2f b) {
    v2f d;
    asm("v_pk_mul_f32 %0, %1, %2 op_sel:[0,0] op_sel_hi:[0,1]"
        : "=v"(d) : "v"(a), "v"(b));
    return d;
}
__device__ __forceinline__ void pk_fma_lo(v2f &acc, v2f a, v2f b) {
    asm("v_pk_fma_f32 %0, %1, %2, %0 op_sel:[0,0,0] op_sel_hi:[0,1,1]"
        : "+v"(acc) : "v"(a), "v"(b));
}
__device__ __forceinline__ void pk_fma_hi(v2f &acc, v2f a, v2f b) {
    asm("v_pk_fma_f32 %0, %1, %2, %0 op_sel:[1,0,0] op_sel_hi:[1,1,1]"
        : "+v"(acc) : "v"(a), "v"(b));
}

// lane^1 partner swap as DPP quad_perm [1,0,3,2] (ctrl 0xB1), proven R10.
__device__ __forceinline__ float pswap(float x)
{
    return __builtin_bit_cast(float,
        __builtin_amdgcn_update_dpp(0, __builtin_bit_cast(int, x),
                                    0xB1, 0xF, 0xF, true));
}

// async DMA: 16B per lane, LDS dest = uniform base + lane*16 (linear).
#define GLOAD_LDS16(gp, lp)                                               \
    __builtin_amdgcn_global_load_lds(                                     \
        (const __attribute__((address_space(1))) void*)(gp),              \
        (__attribute__((address_space(3))) void*)(lp), 16, 0, 0)

#define AE(p, q) A[(p) < (q) ? (p) : (q)][(p) < (q) ? (q) : (p)]

// One power step: n = A*y (slab matvec, packed), y <- n, acc += wk * n.
#define POW_STEP(wk)                                                      \
    {                                                                     \
        const v2f wv = (v2f){(wk), (wk)};                                 \
        _Pragma("unroll")                                                 \
        for (int j = 0; j < 2; ++j) {                                     \
            v2f n[8];                                                     \
            _Pragma("unroll")                                             \
            for (int p = 0; p < 8; ++p) {                                 \
                v2f a = pk_mul_lo(Ar[p][0], y[j][0]);                     \
                pk_fma_hi(a, Ar[p][0], y[j][1]);                          \
                pk_fma_lo(a, Ar[p][1], y[j][2]);                          \
                pk_fma_hi(a, Ar[p][1], y[j][3]);                          \
                pk_fma_lo(a, Ar[p][2], y[j][4]);                          \
                pk_fma_hi(a, Ar[p][2], y[j][5]);                          \
                pk_fma_lo(a, Ar[p][3], y[j][6]);                          \
                pk_fma_hi(a, Ar[p][3], y[j][7]);                          \
                n[p] = a;                                                 \
            }                                                             \
            _Pragma("unroll")                                             \
            for (int p = 0; p < 8; ++p) {                                 \
                y[j][p] = n[p];                                           \
                pk_fma(acc[j][p], wv, n[p]);                              \
            }                                                             \
        }                                                                 \
    }

__global__ __launch_bounds__(256, 2)
void ns_poly_kernel(const float* __restrict__ in,
                    const float* __restrict__ wp,
                    float* __restrict__ out)
{
    __shared__ float4 lds[2048];                      // 32 KB: 4 waves x 8 KB

    const int tid  = threadIdx.x;
    const int wave = tid >> 6;
    const int lane = tid & 63;
    const int l    = lane >> 1;                       // matrix-in-wave 0..31
    const int h    = lane & 1;                        // column-half owner

    const float w0 = wp[0], w1 = wp[1], w2 = wp[2], w3 = wp[3];
    const float w4 = wp[4], w5 = wp[5], w6 = wp[6], w7 = wp[7];

    float4* L = lds + wave * 512;                     // wave-private 8 KB

    // this wave's first chunk (float4 units): 32 matrices x 16 chunks
    const size_t base =
        ((size_t)blockIdx.x * 128 + (size_t)wave * 32) * 16;
    const float4* __restrict__ gin  = reinterpret_cast<const float4*>(in);
    float4*       __restrict__ gout = reinterpret_cast<float4*>(out);

    // ---- DMA stage: pre-swizzled global source -> linear LDS ----
#pragma unroll
    for (int it = 0; it < 8; ++it) {
        const int C = it * 64 + lane;
        const int Cs = C ^ (((C >> 4) & 3) << 1);
        GLOAD_LDS16(gin + base + Cs, L + it * 64);
    }
    asm volatile("s_waitcnt vmcnt(0)" ::: "memory");
    __builtin_amdgcn_sched_barrier(0);

    // ---- fragment read: rows g=0..7, my col-half (natural layout) ----
    v2f y[2][8];
#pragma unroll
    for (int g = 0; g < 8; ++g) {
        const int f4 = (l * 16 + g * 2 + h) ^ ((l & 3) << 1);
        const float4 v = L[f4];
        y[0][g] = (v2f){v.x, v.y};
        y[1][g] = (v2f){v.z, v.w};
    }

    // ---- partial Gram over my 4 columns (upper triangle) ----
    float S[8][8];
#pragma unroll
    for (int p = 0; p < 8; ++p)
#pragma unroll
        for (int q = p; q < 8; ++q) {
            v2f a = pk_mul(y[0][p], y[0][q]);
            pk_fma(a, y[1][p], y[1][q]);
            S[p][q] = a.x + a.y;
        }

    // ---- A = I - S - partner(S): pswap at same (p,q) ----
    float A[8][8];
#pragma unroll
    for (int p = 0; p < 8; ++p)
#pragma unroll
        for (int q = p; q < 8; ++q) {
            const float other = pswap(S[p][q]);
            A[p][q] = (p == q ? 1.0f : 0.0f) - S[p][q] - other;
        }

    // ---- pack A rows into q-pairs for op_sel broadcast ----
    v2f Ar[8][4];
#pragma unroll
    for (int p = 0; p < 8; ++p)
#pragma unroll
        for (int jq = 0; jq < 4; ++jq)
            Ar[p][jq] = (v2f){AE(p, 2 * jq), AE(p, 2 * jq + 1)};

    // ---- power iteration: acc = (1+w7) x; 7x { y <- A y; acc += wk y } ----
    v2f acc[2][8];
    const v2f w7v = (v2f){1.0f + w7, 1.0f + w7};
#pragma unroll
    for (int j = 0; j < 2; ++j)
#pragma unroll
        for (int p = 0; p < 8; ++p)
            acc[j][p] = pk_mul(w7v, y[j][p]);

    POW_STEP(w0);
    POW_STEP(w1);
    POW_STEP(w2);
    POW_STEP(w3);
    POW_STEP(w4);
    POW_STEP(w5);
    POW_STEP(w6);

    // ---- fragment write back to LDS (swizzled positions) ----
#pragma unroll
    for (int g = 0; g < 8; ++g) {
        const int f4 = (l * 16 + g * 2 + h) ^ ((l & 3) << 1);
        L[f4] = make_float4(acc[0][g].x, acc[0][g].y,
                            acc[1][g].x, acc[1][g].y);
    }
    asm volatile("s_waitcnt lgkmcnt(0)" ::: "memory");

    // ---- drain: LDS -> contiguous global stores ----
#pragma unroll
    for (int it = 0; it < 8; ++it) {
        const int C = it * 64 + lane;
        gout[base + C] = L[C ^ (((C >> 4) & 3) << 1)];
    }
}

extern "C" void kernel_launch(void* const* d_in, const int* in_sizes, int n_in,
                              void* d_out, int out_size, void* d_ws, size_t ws_size,
                              hipStream_t stream)
{
    const float* in = (const float*)d_in[0];
    const float* w  = (const float*)d_in[1];
    float* outp     = (float*)d_out;

    const int nmat   = in_sizes[0] / 64;   // 262144 matrices
    const int blocks = nmat / 128;         // 2048 blocks, 128 matrices each
    ns_poly_kernel<<<blocks, 256, 0, stream>>>(in, w, outp);
}